// Round 2
// baseline (1090.110 us; speedup 1.0000x reference)
//
#include <hip/hip_runtime.h>
#include <stdint.h>

#define R_N   5
#define NUSR  4096
#define I_DIM 2048
#define H_DIM 512
#define KTOT  20480   /* R_N * 4096 */
#define BM 128
#define BN 128
#define BK 32
#define APAD 40       /* As row stride in elements (BK + 8) to kill bank conflicts */

using bf16x8 = __attribute__((ext_vector_type(8))) short;
using f32x4  = __attribute__((ext_vector_type(4))) float;

__device__ __forceinline__ unsigned short f2bf(float f) {
  unsigned int u = __float_as_uint(f);
  u += 0x7FFFu + ((u >> 16) & 1u);          // RNE
  return (unsigned short)(u >> 16);
}
__device__ __forceinline__ unsigned int pk2bf(float a, float b) {
  unsigned int ua = __float_as_uint(a); ua += 0x7FFFu + ((ua >> 16) & 1u);
  unsigned int ub = __float_as_uint(b); ub += 0x7FFFu + ((ub >> 16) & 1u);
  return (ua >> 16) | (ub & 0xFFFF0000u);
}
__device__ __forceinline__ void gl_lds16(const void* g, void* l) {
  __builtin_amdgcn_global_load_lds(
      (const __attribute__((address_space(1))) unsigned int*)g,
      (__attribute__((address_space(3))) unsigned int*)l, 16, 0, 0);
}

// ---------------------------------------------------------------------------
// Kernel 1: w_cum = cumsum(u_weight, axis=0), emitted transposed per relation:
//   wcumT[(r*512 + h)][i] = w_cum[r][i][h]   (bf16, k(=i)-contiguous rows)
// ---------------------------------------------------------------------------
__global__ __launch_bounds__(256) void wcum_kernel(
    const float* __restrict__ w, unsigned short* __restrict__ wcumT) {
  __shared__ float sT[64][68];
  const int t  = threadIdx.x;
  const int i0 = blockIdx.x * 64, h0 = blockIdx.y * 64;
  const int il = t >> 2, hs = (t & 3) * 16;   // load mapping: row il, 16 h
  float4 c[4];
#pragma unroll
  for (int j = 0; j < 4; j++) { c[j].x = 0.f; c[j].y = 0.f; c[j].z = 0.f; c[j].w = 0.f; }
  const int hl = t >> 2, is = (t & 3) * 16;   // store mapping: h-row hl, 16 i
  for (int r = 0; r < R_N; r++) {
    const float* src = w + (size_t)r * I_DIM * H_DIM + (size_t)(i0 + il) * H_DIM + h0 + hs;
#pragma unroll
    for (int j = 0; j < 4; j++) {
      float4 v = ((const float4*)src)[j];
      c[j].x += v.x; c[j].y += v.y; c[j].z += v.z; c[j].w += v.w;
    }
    __syncthreads();
#pragma unroll
    for (int j = 0; j < 4; j++) *(float4*)&sT[il][hs + 4 * j] = c[j];
    __syncthreads();
    unsigned int pk[8];
#pragma unroll
    for (int j = 0; j < 8; j++)
      pk[j] = (unsigned int)f2bf(sT[is + 2 * j][hl]) |
              ((unsigned int)f2bf(sT[is + 2 * j + 1][hl]) << 16);
    unsigned short* dst = wcumT + (size_t)(r * H_DIM + h0 + hl) * I_DIM + i0 + is;
    uint4 q0; q0.x = pk[0]; q0.y = pk[1]; q0.z = pk[2]; q0.w = pk[3];
    uint4 q1; q1.x = pk[4]; q1.y = pk[5]; q1.z = pk[6]; q1.w = pk[7];
    ((uint4*)dst)[0] = q0; ((uint4*)dst)[1] = q1;
  }
}

// ---------------------------------------------------------------------------
// Kernel 2: tmpT = (feat @ w_cum)^T per relation, bf16.
//   A = [u_feat; v_feat]  (M=8192, K=2048, f32, cvt on the fly)
//   B = wcumT [2560][2048]  (B^T layout, global_load_lds + XOR swizzle)
//   out: tmpT_x[h][r*4096 + m]  ([512][20480] bf16, k-contiguous for kernel 3)
// ---------------------------------------------------------------------------
__global__ __launch_bounds__(256, 2) void gemm_feat(
    const float* __restrict__ u_feat, const float* __restrict__ v_feat,
    const unsigned short* __restrict__ wcumT,
    unsigned short* __restrict__ tmpT_u, unsigned short* __restrict__ tmpT_v) {
  __shared__ unsigned short As[BM * APAD];
  __shared__ unsigned short Bs[BN * BK];
  const int t = threadIdx.x;
  const int lane = t & 63, lid = lane & 15, quad = lane >> 4;
  const int wave = t >> 6, wm = wave >> 1, wn = wave & 1;
  const int m0 = blockIdx.x * BM;          // 0..8191
  const int n0 = blockIdx.y * BN;          // 0..2559
  const bool is_u = (m0 < NUSR);
  const float* A = is_u ? u_feat : v_feat;
  const int mbase = m0 & (NUSR - 1);
  const int arow = t >> 1, akoff = (t & 1) * 16;
  const float* aptr = A + (size_t)(mbase + arow) * I_DIM + akoff;
  unsigned short* awr = &As[arow * APAD + akoff];

  f32x4 acc[4][4];
#pragma unroll
  for (int i = 0; i < 4; i++)
#pragma unroll
    for (int j = 0; j < 4; j++) acc[i][j] = f32x4{0.f, 0.f, 0.f, 0.f};

  for (int kc = 0; kc < I_DIM; kc += BK) {
    __syncthreads();
    // B: async global->LDS, swizzled granules
#pragma unroll
    for (int s = 0; s < 2; s++) {
      int g = t + s * 256;
      int n = g >> 2, q = (g & 3) ^ ((n >> 1) & 3);
      gl_lds16(wcumT + (size_t)(n0 + n) * I_DIM + kc + q * 8, &Bs[g * 8]);
    }
    // A: f32 load -> bf16 cvt -> LDS (padded rows)
    float4 av[4];
#pragma unroll
    for (int j = 0; j < 4; j++) av[j] = *(const float4*)(aptr + kc + 4 * j);
    unsigned int pk[8];
#pragma unroll
    for (int j = 0; j < 4; j++) {
      pk[2 * j]     = pk2bf(av[j].x, av[j].y);
      pk[2 * j + 1] = pk2bf(av[j].z, av[j].w);
    }
    uint4 q0; q0.x = pk[0]; q0.y = pk[1]; q0.z = pk[2]; q0.w = pk[3];
    uint4 q1; q1.x = pk[4]; q1.y = pk[5]; q1.z = pk[6]; q1.w = pk[7];
    ((uint4*)awr)[0] = q0; ((uint4*)awr)[1] = q1;
    __syncthreads();

    bf16x8 af[4], bfr[4];
#pragma unroll
    for (int ti = 0; ti < 4; ti++)
      af[ti] = *(const bf16x8*)&As[(wm * 64 + ti * 16 + lid) * APAD + quad * 8];
#pragma unroll
    for (int tj = 0; tj < 4; tj++) {
      int n = wn * 64 + tj * 16 + lid;
      int g = n * 4 + (quad ^ ((n >> 1) & 3));
      bfr[tj] = *(const bf16x8*)&Bs[g * 8];
    }
#pragma unroll
    for (int ti = 0; ti < 4; ti++)
#pragma unroll
      for (int tj = 0; tj < 4; tj++)
        acc[ti][tj] = __builtin_amdgcn_mfma_f32_16x16x32_bf16(af[ti], bfr[tj], acc[ti][tj], 0, 0, 0);
  }

  // epilogue: transposed bf16 store (4 consecutive k = 8B per lane-tile)
  const int r = n0 >> 9, h0 = n0 & 511;
  unsigned short* dstT = is_u ? tmpT_u : tmpT_v;
#pragma unroll
  for (int ti = 0; ti < 4; ti++)
#pragma unroll
    for (int tj = 0; tj < 4; tj++) {
      int h = h0 + wn * 64 + tj * 16 + lid;
      int m = mbase + wm * 64 + ti * 16 + quad * 4;
      f32x4 v = acc[ti][tj];
      ushort4 o;
      o.x = f2bf(v[0]); o.y = f2bf(v[1]); o.z = f2bf(v[2]); o.w = f2bf(v[3]);
      *(ushort4*)(dstT + (size_t)h * KTOT + r * 4096 + m) = o;
    }
}

// ---------------------------------------------------------------------------
// Kernel 3: z partials. A = support/support_t [4096][20480] f32 (streamed,
// cvt to bf16), B = tmpT [512][20480] bf16 (B^T layout). K split in 4 chunks,
// f32 atomicAdd into zacc[2][4096][512].
// ---------------------------------------------------------------------------
__global__ __launch_bounds__(256, 2) void gemm_spmm(
    const float* __restrict__ support, const float* __restrict__ support_t,
    const unsigned short* __restrict__ tmpT_u, const unsigned short* __restrict__ tmpT_v,
    float* __restrict__ zacc) {
  __shared__ unsigned short As[BM * APAD];
  __shared__ unsigned short Bs[BN * BK];
  const int t = threadIdx.x;
  const int lane = t & 63, lid = lane & 15, quad = lane >> 4;
  const int wave = t >> 6, wm = wave >> 1, wn = wave & 1;
  const int m0 = blockIdx.x * BM;          // 0..4095
  const int h0 = blockIdx.y * BN;          // 0..511
  const int outi = blockIdx.z >> 2, chunk = blockIdx.z & 3;
  const float* A = outi ? support_t : support;
  const unsigned short* B = outi ? tmpT_u : tmpT_v;
  const int k0 = chunk * (KTOT / 4);       // 5120-wide chunk
  const int arow = t >> 1, akoff = (t & 1) * 16;
  const float* aptr = A + (size_t)(m0 + arow) * KTOT + k0 + akoff;
  unsigned short* awr = &As[arow * APAD + akoff];

  f32x4 acc[4][4];
#pragma unroll
  for (int i = 0; i < 4; i++)
#pragma unroll
    for (int j = 0; j < 4; j++) acc[i][j] = f32x4{0.f, 0.f, 0.f, 0.f};

  for (int kc = 0; kc < KTOT / 4; kc += BK) {
    __syncthreads();
#pragma unroll
    for (int s = 0; s < 2; s++) {
      int g = t + s * 256;
      int n = g >> 2, q = (g & 3) ^ ((n >> 1) & 3);
      gl_lds16(B + (size_t)(h0 + n) * KTOT + k0 + kc + q * 8, &Bs[g * 8]);
    }
    float4 av[4];
#pragma unroll
    for (int j = 0; j < 4; j++) av[j] = *(const float4*)(aptr + kc + 4 * j);
    unsigned int pk[8];
#pragma unroll
    for (int j = 0; j < 4; j++) {
      pk[2 * j]     = pk2bf(av[j].x, av[j].y);
      pk[2 * j + 1] = pk2bf(av[j].z, av[j].w);
    }
    uint4 q0; q0.x = pk[0]; q0.y = pk[1]; q0.z = pk[2]; q0.w = pk[3];
    uint4 q1; q1.x = pk[4]; q1.y = pk[5]; q1.z = pk[6]; q1.w = pk[7];
    ((uint4*)awr)[0] = q0; ((uint4*)awr)[1] = q1;
    __syncthreads();

    bf16x8 af[4], bfr[4];
#pragma unroll
    for (int ti = 0; ti < 4; ti++)
      af[ti] = *(const bf16x8*)&As[(wm * 64 + ti * 16 + lid) * APAD + quad * 8];
#pragma unroll
    for (int tj = 0; tj < 4; tj++) {
      int n = wn * 64 + tj * 16 + lid;
      int g = n * 4 + (quad ^ ((n >> 1) & 3));
      bfr[tj] = *(const bf16x8*)&Bs[g * 8];
    }
#pragma unroll
    for (int ti = 0; ti < 4; ti++)
#pragma unroll
      for (int tj = 0; tj < 4; tj++)
        acc[ti][tj] = __builtin_amdgcn_mfma_f32_16x16x32_bf16(af[ti], bfr[tj], acc[ti][tj], 0, 0, 0);
  }

  float* dst = zacc + (size_t)outi * NUSR * H_DIM;
#pragma unroll
  for (int ti = 0; ti < 4; ti++)
#pragma unroll
    for (int tj = 0; tj < 4; tj++) {
      int m = m0 + wm * 64 + ti * 16 + quad * 4;
      int h = h0 + wn * 64 + tj * 16 + lid;
      float* p = dst + (size_t)m * H_DIM + h;
      atomicAdd(p,             acc[ti][tj][0]);
      atomicAdd(p + H_DIM,     acc[ti][tj][1]);
      atomicAdd(p + 2 * H_DIM, acc[ti][tj][2]);
      atomicAdd(p + 3 * H_DIM, acc[ti][tj][3]);
    }
}

// ---------------------------------------------------------------------------
// Kernel 4: out = f32(relu(zacc + bias[h]))  -- d_out is FLOAT32 (ref dtype)
// ---------------------------------------------------------------------------
__global__ __launch_bounds__(256) void bias_relu(
    const float* __restrict__ zacc, const float* __restrict__ bias,
    float* __restrict__ out) {
  int e = (blockIdx.x * 256 + threadIdx.x) * 4;   // < 2*4096*512
  float4 v = *(const float4*)(zacc + e);
  int h = e & (H_DIM - 1);
  float4 b = *(const float4*)(bias + h);
  float4 o;
  o.x = fmaxf(v.x + b.x, 0.f);
  o.y = fmaxf(v.y + b.y, 0.f);
  o.z = fmaxf(v.z + b.z, 0.f);
  o.w = fmaxf(v.w + b.w, 0.f);
  *(float4*)(out + e) = o;
}

extern "C" void kernel_launch(void* const* d_in, const int* in_sizes, int n_in,
                              void* d_out, int out_size, void* d_ws, size_t ws_size,
                              hipStream_t stream) {
  const float* u_feat    = (const float*)d_in[0];
  const float* v_feat    = (const float*)d_in[1];
  const float* support   = (const float*)d_in[2];
  const float* support_t = (const float*)d_in[3];
  const float* u_weight  = (const float*)d_in[4];
  const float* u_bias    = (const float*)d_in[5];

  char* ws = (char*)d_ws;
  unsigned short* wcumT  = (unsigned short*)(ws);                 // 10,485,760 B
  unsigned short* tmpT_u = (unsigned short*)(ws + 10485760);      // 20,971,520 B
  unsigned short* tmpT_v = (unsigned short*)(ws + 31457280);      // 20,971,520 B
  float*          zacc   = (float*)(ws + 52428800);               // 16,777,216 B

  hipMemsetAsync(zacc, 0, (size_t)2 * NUSR * H_DIM * sizeof(float), stream);
  wcum_kernel<<<dim3(32, 8), 256, 0, stream>>>(u_weight, wcumT);
  gemm_feat<<<dim3(64, 20), 256, 0, stream>>>(u_feat, v_feat, wcumT, tmpT_u, tmpT_v);
  gemm_spmm<<<dim3(32, 4, 8), 256, 0, stream>>>(support, support_t, tmpT_u, tmpT_v, zacc);
  bias_relu<<<4096, 256, 0, stream>>>(zacc, u_bias, (float*)d_out);
}